// Round 11
// baseline (11906.044 us; speedup 1.0000x reference)
//
#include <hip/hip_runtime.h>
#include <hip/hip_fp16.h>
#include <cstdint>
#include <cstddef>

#define N_E 2048
#define N_I 512
#define N_TOT 2560
#define BATCH 64
#define TSTEPS 512
#define INDIM 128
#define GD 32                 // gather batch depth (one memory round-trip for ns<=32)

// ------------------------------------------------------------------
// Dense signed-relu weight table Wd[pre][post] (fp16), tiled transpose.
// ------------------------------------------------------------------
#define TS 64
__global__ __launch_bounds__(256) void build_wd_kernel(
    const float* __restrict__ Wee, const float* __restrict__ Wie,
    const float* __restrict__ Wei, const float* __restrict__ Wii,
    __half* __restrict__ Wd)
{
    __shared__ float tile[TS][TS + 1];
    int P0 = blockIdx.x * TS;   // pre base
    int Q0 = blockIdx.y * TS;   // post base
    int tx = threadIdx.x & 63, ty = threadIdx.x >> 6;

    const float* W; int ldw, po_off, pr_off; float sign;
    bool preE = (P0 < N_E), postE = (Q0 < N_E);
    if (postE && preE)        { W = Wee; ldw = N_E; po_off = 0;   pr_off = 0;   sign =  1.f; }
    else if (!postE && preE)  { W = Wie; ldw = N_E; po_off = N_E; pr_off = 0;   sign =  1.f; }
    else if (postE && !preE)  { W = Wei; ldw = N_I; po_off = 0;   pr_off = N_E; sign = -1.f; }
    else                      { W = Wii; ldw = N_I; po_off = N_E; pr_off = N_E; sign = -1.f; }

    for (int r = ty; r < TS; r += 4) {
        int post = Q0 + r, pre = P0 + tx;
        float v = W[(size_t)(post - po_off) * ldw + (pre - pr_off)];
        tile[r][tx] = (v > 0.f) ? sign * v : 0.f;
    }
    __syncthreads();
    for (int r = ty; r < TS; r += 4) {
        int pre = P0 + r, post = Q0 + tx;
        Wd[(size_t)pre * N_TOT + post] = __float2half(tile[tx][r]);
    }
}

// ------------------------------------------------------------------
// Input projection GEMM (unchanged)
// ------------------------------------------------------------------
#define PBM 128
#define PBN 64
#define PBK 32
__global__ __launch_bounds__(256) void proj_kernel(
    const float* __restrict__ x, const float* __restrict__ We, const float* __restrict__ Wi,
    float* __restrict__ out, int t0)
{
    __shared__ __align__(16) float As[PBK][132];
    __shared__ __align__(16) float Bs[PBK][68];
    int tid = threadIdx.x;
    int bx = blockIdx.x, by = blockIdx.y;
    int tx = tid & 15, ty = tid >> 4;
    float acc[8][4];
#pragma unroll
    for (int i = 0; i < 8; ++i)
#pragma unroll
        for (int j = 0; j < 4; ++j) acc[i][j] = 0.0f;

    for (int kb = 0; kb < INDIM; kb += PBK) {
#pragma unroll
        for (int it = 0; it < 4; ++it) {
            int idx = it * 256 + tid;
            int kq = idx & 7, ml = idx >> 3;
            int m = by * PBM + ml;
            int b = m & 63, tl = m >> 6;
            const float* arow = x + ((size_t)b * TSTEPS + (size_t)(t0 + tl)) * INDIM;
            float4 v = *(const float4*)(arow + kb + kq * 4);
            As[kq * 4 + 0][ml] = v.x; As[kq * 4 + 1][ml] = v.y;
            As[kq * 4 + 2][ml] = v.z; As[kq * 4 + 3][ml] = v.w;
        }
#pragma unroll
        for (int it = 0; it < 2; ++it) {
            int idx = it * 256 + tid;
            int kq = idx & 7, nl = idx >> 3;
            int n = bx * PBN + nl;
            const float* brow = (n < N_E) ? (We + (size_t)n * INDIM)
                                          : (Wi + (size_t)(n - N_E) * INDIM);
            float4 v = *(const float4*)(brow + kb + kq * 4);
            Bs[kq * 4 + 0][nl] = v.x; Bs[kq * 4 + 1][nl] = v.y;
            Bs[kq * 4 + 2][nl] = v.z; Bs[kq * 4 + 3][nl] = v.w;
        }
        __syncthreads();
#pragma unroll
        for (int k = 0; k < PBK; ++k) {
            float4 a0 = *(const float4*)&As[k][ty * 8];
            float4 a1 = *(const float4*)&As[k][ty * 8 + 4];
            float4 b0 = *(const float4*)&Bs[k][tx * 4];
            float a[8] = {a0.x, a0.y, a0.z, a0.w, a1.x, a1.y, a1.z, a1.w};
            float bb[4] = {b0.x, b0.y, b0.z, b0.w};
#pragma unroll
            for (int i = 0; i < 8; ++i)
#pragma unroll
                for (int j = 0; j < 4; ++j)
                    acc[i][j] = fmaf(a[i], bb[j], acc[i][j]);
        }
        __syncthreads();
    }
#pragma unroll
    for (int i = 0; i < 8; ++i) {
        int m = by * PBM + ty * 8 + i;
        float4 o = make_float4(acc[i][0], acc[i][1], acc[i][2], acc[i][3]);
        *(float4*)(out + (size_t)m * N_TOT + bx * PBN + tx * 4) = o;
    }
}

__device__ __forceinline__ float inline_proj(const float* __restrict__ x,
                                             const float* __restrict__ We_in,
                                             const float* __restrict__ Wi_in,
                                             int b, int t, int n)
{
    const float* xr = x + ((size_t)b * TSTEPS + (size_t)t) * INDIM;
    const float* wr = (n < N_E) ? (We_in + (size_t)n * INDIM)
                                : (Wi_in + (size_t)(n - N_E) * INDIM);
    float a = 0.f;
#pragma unroll
    for (int k = 0; k < INDIM; k += 4) {
        float4 w = *(const float4*)(wr + k);
        float4 xv = *(const float4*)(xr + k);
        a = fmaf(w.x, xv.x, a); a = fmaf(w.y, xv.y, a);
        a = fmaf(w.z, xv.z, a); a = fmaf(w.w, xv.w, a);
    }
    return a;
}

// ------------------------------------------------------------------
// PULL sim, improved: 32-deep predicated batched gather (one memory
// round trip for ns<=32) + register prefetch of next-step input.
// ------------------------------------------------------------------
__global__ __launch_bounds__(640) void sim_kernel(
    const float* __restrict__ i_inp,
    const float* __restrict__ x, const float* __restrict__ We_in, const float* __restrict__ Wi_in,
    const __half* __restrict__ Wd,
    float* __restrict__ gv, float* __restrict__ gi, unsigned* __restrict__ g_cnt,
    int* __restrict__ g_list, int* __restrict__ g_nspk,
    int t0, int tc, int first)
{
    __shared__ int list_s[2][N_TOT];
    __shared__ int nspk_s[2];

    int b = blockIdx.x, tid = threadIdx.x, lane = tid & 63;
    int p0 = tid * 4;
    bool isE = (tid < 512);
    float tm = isE ? 0.05f : 0.1f;

    float v0, v1, v2, v3, c0, c1, c2, c3;
    unsigned n0c = 0u, n1c = 0u, n2c = 0u, n3c = 0u;
    if (first) {
        v0 = v1 = v2 = v3 = 0.f; c0 = c1 = c2 = c3 = 0.f;
        if (tid == 0) nspk_s[0] = 0;
    } else {
        float4 vv = *(const float4*)(gv + (size_t)b * N_TOT + p0);
        float4 cc = *(const float4*)(gi + (size_t)b * N_TOT + p0);
        v0 = vv.x; v1 = vv.y; v2 = vv.z; v3 = vv.w;
        c0 = cc.x; c1 = cc.y; c2 = cc.z; c3 = cc.w;
        if (isE) {
            uint4 q = *(const uint4*)(g_cnt + (size_t)b * N_E + p0);
            n0c = q.x; n1c = q.y; n2c = q.z; n3c = q.w;
        }
        if (tid == 0) nspk_s[0] = g_nspk[b];
    }
    __syncthreads();
    if (!first) {
        int n0 = nspk_s[0];
        for (int s = tid; s < n0; s += 640) list_s[0][s] = g_list[(size_t)b * N_TOT + s];
    }
    __syncthreads();

    const unsigned short* Wdu = (const unsigned short*)Wd;

    // prologue: input for step 0
    float4 pf;
    if (i_inp) pf = *(const float4*)(i_inp + (size_t)b * N_TOT + p0);

    for (int tl = 0; tl < tc; ++tl) {
        int cur = tl & 1, nxt = cur ^ 1;
        if (tid == 0) nspk_s[nxt] = 0;

        float I0, I1, I2, I3;
        float4 pfn;
        if (i_inp) {
            I0 = pf.x; I1 = pf.y; I2 = pf.z; I3 = pf.w;
            if (tl + 1 < tc)   // issue next step's load NOW; consumed next iter
                pfn = *(const float4*)(i_inp + ((size_t)(tl + 1) * BATCH + b) * N_TOT + p0);
        } else {
            const float* xr = x + ((size_t)b * TSTEPS + (size_t)(t0 + tl)) * INDIM;
            const float* w0 = isE ? (We_in + (size_t)p0 * INDIM)
                                  : (Wi_in + (size_t)(p0 - N_E) * INDIM);
            I0 = I1 = I2 = I3 = 0.f;
            for (int k = 0; k < INDIM; ++k) {
                float xv = xr[k];
                I0 = fmaf(w0[k], xv, I0);
                I1 = fmaf(w0[INDIM + k], xv, I1);
                I2 = fmaf(w0[2 * INDIM + k], xv, I2);
                I3 = fmaf(w0[3 * INDIM + k], xv, I3);
            }
        }

        // gather: batched predicated loads, all issued before any use
        int ns = nspk_s[cur];
        const int* lst = list_s[cur];
        for (int s0 = 0; s0 < ns; s0 += GD) {
            int take = ns - s0; if (take > GD) take = GD;
            ushort4 w[GD];
#pragma unroll
            for (int k = 0; k < GD; ++k) {
                if (k < take) {
                    int j = lst[s0 + k];
                    w[k] = *(const ushort4*)(Wdu + (size_t)j * N_TOT + p0);
                }
            }
#pragma unroll
            for (int k = 0; k < GD; ++k) {
                if (k < take) {
                    I0 += __half2float(__ushort_as_half(w[k].x));
                    I1 += __half2float(__ushort_as_half(w[k].y));
                    I2 += __half2float(__ushort_as_half(w[k].z));
                    I3 += __half2float(__ushort_as_half(w[k].w));
                }
            }
        }

        // LIF in registers
        float vd0 = v0 + tm * (c0 - v0); bool z0 = vd0 > 1.0f; v0 = z0 ? 0.f : vd0; c0 = 0.8f * c0 + I0;
        float vd1 = v1 + tm * (c1 - v1); bool z1 = vd1 > 1.0f; v1 = z1 ? 0.f : vd1; c1 = 0.8f * c1 + I1;
        float vd2 = v2 + tm * (c2 - v2); bool z2 = vd2 > 1.0f; v2 = z2 ? 0.f : vd2; c2 = 0.8f * c2 + I2;
        float vd3 = v3 + tm * (c3 - v3); bool z3 = vd3 > 1.0f; v3 = z3 ? 0.f : vd3; c3 = 0.8f * c3 + I3;
        if (isE) { n0c += z0; n1c += z1; n2c += z2; n3c += z3; }

        __syncthreads();   // barrier 1

        unsigned long long m0 = __ballot(z0), m1 = __ballot(z1);
        unsigned long long m2 = __ballot(z2), m3 = __ballot(z3);
        int w0c = __popcll(m0), w1c = __popcll(m1), w2c = __popcll(m2), w3c = __popcll(m3);
        int tot = w0c + w1c + w2c + w3c;
        if (tot) {
            int base = 0;
            if (lane == 0) base = atomicAdd(&nspk_s[nxt], tot);
            base = __shfl(base, 0);
            unsigned long long pre = (1ull << lane) - 1ull;
            if (z0) list_s[nxt][base + __popcll(m0 & pre)] = p0;
            if (z1) list_s[nxt][base + w0c + __popcll(m1 & pre)] = p0 + 1;
            if (z2) list_s[nxt][base + w0c + w1c + __popcll(m2 & pre)] = p0 + 2;
            if (z3) list_s[nxt][base + w0c + w1c + w2c + __popcll(m3 & pre)] = p0 + 3;
        }
        __syncthreads();   // barrier 2
        pf = pfn;
    }

    *(float4*)(gv + (size_t)b * N_TOT + p0) = make_float4(v0, v1, v2, v3);
    *(float4*)(gi + (size_t)b * N_TOT + p0) = make_float4(c0, c1, c2, c3);
    if (isE) *(uint4*)(g_cnt + (size_t)b * N_E + p0) = make_uint4(n0c, n1c, n2c, n3c);
    int fin = tc & 1;
    if (tid == 0) g_nspk[b] = nspk_s[fin];
    for (int s = tid; s < nspk_s[fin]; s += 640) g_list[(size_t)b * N_TOT + s] = list_s[fin][s];
}

// ------------------------------------------------------------------
// PROBES: pull structure with FORCED spike count, optional barriers /
// input load. Dummy state out. Identified in rocprof by dispatch order:
// PA<0,1,1>  PB<0,0,1>  PC<0,1,0>  PD<32,1,1>, each 2048 steps.
// ------------------------------------------------------------------
template<int FORCED, int BAR, int INPUT>
__global__ __launch_bounds__(640) void sim_probe(
    const float* __restrict__ i_inp, const __half* __restrict__ Wd,
    float* __restrict__ dv, float* __restrict__ di, unsigned* __restrict__ dcnt,
    int tc, int steps)
{
    __shared__ int list_s[2][N_TOT];
    __shared__ int nspk_s[2];

    int b = blockIdx.x, tid = threadIdx.x, lane = tid & 63;
    int p0 = tid * 4;
    bool isE = (tid < 512);
    float tm = isE ? 0.05f : 0.1f;

    float v0 = 0, v1 = 0, v2 = 0, v3 = 0, c0 = 0, c1 = 0, c2 = 0, c3 = 0;
    unsigned n0c = 0, n1c = 0, n2c = 0, n3c = 0;
    if (tid == 0) { nspk_s[0] = FORCED; nspk_s[1] = FORCED; }
    for (int s = tid; s < FORCED; s += 640)
        list_s[0][s] = (int)(((unsigned)s * 2017u) % (unsigned)N_TOT);
    __syncthreads();

    const unsigned short* Wdu = (const unsigned short*)Wd;
    float4 pf = make_float4(0, 0, 0, 0);
    if (INPUT) pf = *(const float4*)(i_inp + (size_t)b * N_TOT + p0);

    for (int tl = 0; tl < steps; ++tl) {
        int cur = tl & 1, nxt = cur ^ 1;

        float I0 = 0, I1 = 0, I2 = 0, I3 = 0;
        float4 pfn = make_float4(0, 0, 0, 0);
        if (INPUT) {
            I0 = pf.x; I1 = pf.y; I2 = pf.z; I3 = pf.w;
            int tn = (tl + 1) & (tc - 1);
            pfn = *(const float4*)(i_inp + ((size_t)tn * BATCH + b) * N_TOT + p0);
        }

        int ns = FORCED;
        const int* lst = list_s[cur];
        for (int s0 = 0; s0 < ns; s0 += GD) {
            int take = ns - s0; if (take > GD) take = GD;
            ushort4 w[GD];
#pragma unroll
            for (int k = 0; k < GD; ++k) {
                if (k < take) {
                    int j = lst[s0 + k];
                    w[k] = *(const ushort4*)(Wdu + (size_t)j * N_TOT + p0);
                }
            }
#pragma unroll
            for (int k = 0; k < GD; ++k) {
                if (k < take) {
                    I0 += __half2float(__ushort_as_half(w[k].x));
                    I1 += __half2float(__ushort_as_half(w[k].y));
                    I2 += __half2float(__ushort_as_half(w[k].z));
                    I3 += __half2float(__ushort_as_half(w[k].w));
                }
            }
        }

        float vd0 = v0 + tm * (c0 - v0); bool z0 = vd0 > 1.0f; v0 = z0 ? 0.f : vd0; c0 = 0.8f * c0 + I0;
        float vd1 = v1 + tm * (c1 - v1); bool z1 = vd1 > 1.0f; v1 = z1 ? 0.f : vd1; c1 = 0.8f * c1 + I1;
        float vd2 = v2 + tm * (c2 - v2); bool z2 = vd2 > 1.0f; v2 = z2 ? 0.f : vd2; c2 = 0.8f * c2 + I2;
        float vd3 = v3 + tm * (c3 - v3); bool z3 = vd3 > 1.0f; v3 = z3 ? 0.f : vd3; c3 = 0.8f * c3 + I3;
        if (isE) { n0c += z0; n1c += z1; n2c += z2; n3c += z3; }

        if (BAR) __syncthreads();

        // real append machinery (timing parity), then forced overwrite
        unsigned long long m0 = __ballot(z0), m1 = __ballot(z1);
        unsigned long long m2 = __ballot(z2), m3 = __ballot(z3);
        int w0c = __popcll(m0), w1c = __popcll(m1), w2c = __popcll(m2), w3c = __popcll(m3);
        int tot = w0c + w1c + w2c + w3c;
        if (tot) {
            int base = 0;
            if (lane == 0) base = atomicAdd(&nspk_s[nxt], tot);
            base = __shfl(base, 0);
            unsigned long long pre = (1ull << lane) - 1ull;
            if (z0 && base < N_TOT - 8) list_s[nxt][base + __popcll(m0 & pre)] = p0;
        }
        for (int s = tid; s < FORCED; s += 640)
            list_s[nxt][s] = (int)((((unsigned)s * 2017u) + (unsigned)(tl + 1) * 911u)
                                   % (unsigned)N_TOT);
        if (tid == 0) nspk_s[nxt] = FORCED;   // re-pin the count
        if (BAR) __syncthreads();
        pf = pfn;
    }

    dv[(size_t)b * N_TOT + p0] = v0 + v1 + v2 + v3;
    di[(size_t)b * N_TOT + p0] = c0 + c1 + c2 + c3;
    dcnt[(size_t)b * N_E + (p0 & (N_E - 1))] = n0c + n1c + n2c + n3c;
}

// ------------------------------------------------------------------
// Readout
// ------------------------------------------------------------------
__global__ __launch_bounds__(256) void readout_kernel(
    const unsigned* __restrict__ g_cnt,
    const float* __restrict__ rw, const float* __restrict__ rb, float* __restrict__ out)
{
    int b = blockIdx.x, tid = threadIdx.x;
    float a0 = 0.f, a1 = 0.f, a2 = 0.f;
    for (int n = tid; n < N_E; n += 256) {
        float c = (float)g_cnt[(size_t)b * N_E + n];
        a0 = fmaf(c, rw[n], a0);
        a1 = fmaf(c, rw[N_E + n], a1);
        a2 = fmaf(c, rw[2 * N_E + n], a2);
    }
#pragma unroll
    for (int off = 32; off > 0; off >>= 1) {
        a0 += __shfl_down(a0, off);
        a1 += __shfl_down(a1, off);
        a2 += __shfl_down(a2, off);
    }
    __shared__ float part[3][4];
    int wid = tid >> 6, lane = tid & 63;
    if (lane == 0) { part[0][wid] = a0; part[1][wid] = a1; part[2][wid] = a2; }
    __syncthreads();
    if (tid == 0) {
        float s0 = part[0][0] + part[0][1] + part[0][2] + part[0][3];
        float s1 = part[1][0] + part[1][1] + part[1][2] + part[1][3];
        float s2 = part[2][0] + part[2][1] + part[2][2] + part[2][3];
        const float inv = 1.0f / 512.0f;
        out[b * 3 + 0] = fmaf(s0, inv, rb[0]);
        out[b * 3 + 1] = fmaf(s1, inv, rb[1]);
        out[b * 3 + 2] = fmaf(s2, inv, rb[2]);
    }
}

// ------------------------------------------------------------------
extern "C" void kernel_launch(void* const* d_in, const int* in_sizes, int n_in,
                              void* d_out, int out_size, void* d_ws, size_t ws_size,
                              hipStream_t stream)
{
    const float* x     = (const float*)d_in[0];
    const float* Wee   = (const float*)d_in[1];
    const float* Wie   = (const float*)d_in[2];
    const float* Wei   = (const float*)d_in[3];
    const float* Wii   = (const float*)d_in[4];
    const float* We_in = (const float*)d_in[5];
    const float* Wi_in = (const float*)d_in[6];
    const float* rw    = (const float*)d_in[7];
    const float* rb    = (const float*)d_in[8];
    float* out = (float*)d_out;
    char* ws = (char*)d_ws;

    size_t off = 0;
    auto alloc = [&](size_t bytes) {
        size_t o = off;
        off = (off + bytes + 255) & ~(size_t)255;
        return o;
    };
    size_t o_wd    = alloc((size_t)N_TOT * N_TOT * 2);
    size_t o_gv    = alloc((size_t)BATCH * N_TOT * 4);
    size_t o_gi    = alloc((size_t)BATCH * N_TOT * 4);
    size_t o_gcnt  = alloc((size_t)BATCH * N_E * 4);
    size_t o_glist = alloc((size_t)BATCH * N_TOT * 4);
    size_t o_gnspk = alloc((size_t)BATCH * 4);
    size_t o_dv    = alloc((size_t)BATCH * N_TOT * 4);
    size_t o_di    = alloc((size_t)BATCH * N_TOT * 4);
    size_t o_dcnt  = alloc((size_t)BATCH * N_E * 4);
    size_t o_iinp  = off;

    int tc = 0;
    if (ws_size > o_iinp) {
        size_t avail = ws_size - o_iinp;
        tc = TSTEPS;
        while (tc >= 2 && (size_t)tc * BATCH * N_TOT * 4 > avail) tc >>= 1;
        if (tc < 2) tc = 0;
    }

    __half*   p_wd    = (__half*)(ws + o_wd);
    float*    p_gv    = (float*)(ws + o_gv);
    float*    p_gi    = (float*)(ws + o_gi);
    unsigned* p_gcnt  = (unsigned*)(ws + o_gcnt);
    int*      p_glist = (int*)(ws + o_glist);
    int*      p_gnspk = (int*)(ws + o_gnspk);
    float*    p_dv    = (float*)(ws + o_dv);
    float*    p_di    = (float*)(ws + o_di);
    unsigned* p_dcnt  = (unsigned*)(ws + o_dcnt);
    float*    p_iinp  = (float*)(ws + o_iinp);

    dim3 wg(N_TOT / TS, N_TOT / TS);
    build_wd_kernel<<<wg, 256, 0, stream>>>(Wee, Wie, Wei, Wii, p_wd);

    if (tc >= 2) {
        dim3 pg(N_TOT / PBN, (tc * BATCH) / PBM);
        proj_kernel<<<pg, 256, 0, stream>>>(x, We_in, Wi_in, p_iinp, 0);

        // ---- probes (identified by dispatch order PA,PB,PC,PD) ----
        const int PSTEPS = 2048;
        sim_probe<0, 1, 1><<<BATCH, 640, 0, stream>>>(p_iinp, p_wd, p_dv, p_di, p_dcnt, tc, PSTEPS);
        sim_probe<0, 0, 1><<<BATCH, 640, 0, stream>>>(p_iinp, p_wd, p_dv, p_di, p_dcnt, tc, PSTEPS);
        sim_probe<0, 1, 0><<<BATCH, 640, 0, stream>>>(p_iinp, p_wd, p_dv, p_di, p_dcnt, tc, PSTEPS);
        sim_probe<32, 1, 1><<<BATCH, 640, 0, stream>>>(p_iinp, p_wd, p_dv, p_di, p_dcnt, tc, PSTEPS);

        // ---- real pipeline ----
        for (int t0 = 0; t0 < TSTEPS; t0 += tc) {
            if (t0 > 0)
                proj_kernel<<<pg, 256, 0, stream>>>(x, We_in, Wi_in, p_iinp, t0);
            sim_kernel<<<BATCH, 640, 0, stream>>>(
                p_iinp, x, We_in, Wi_in, p_wd,
                p_gv, p_gi, p_gcnt, p_glist, p_gnspk,
                t0, tc, (t0 == 0) ? 1 : 0);
        }
    } else {
        sim_kernel<<<BATCH, 640, 0, stream>>>(
            nullptr, x, We_in, Wi_in, p_wd,
            p_gv, p_gi, p_gcnt, p_glist, p_gnspk,
            0, TSTEPS, 1);
    }

    readout_kernel<<<BATCH, 256, 0, stream>>>(p_gcnt, rw, rb, out);
}

// Round 12
// 2503.524 us; speedup vs baseline: 4.7557x; 4.7557x over previous
//
#include <hip/hip_runtime.h>
#include <hip/hip_fp16.h>
#include <cstdint>
#include <cstddef>

#define N_E 2048
#define N_I 512
#define N_TOT 2560
#define BATCH 64
#define TSTEPS 512
#define INDIM 128
#define GD 32                 // gather batch depth (one memory round-trip for ns<=32)

// ------------------------------------------------------------------
// Dense signed-relu weight table Wd[pre][post] (fp16), tiled transpose.
// ------------------------------------------------------------------
#define TS 64
__global__ __launch_bounds__(256) void build_wd_kernel(
    const float* __restrict__ Wee, const float* __restrict__ Wie,
    const float* __restrict__ Wei, const float* __restrict__ Wii,
    __half* __restrict__ Wd)
{
    __shared__ float tile[TS][TS + 1];
    int P0 = blockIdx.x * TS;   // pre base
    int Q0 = blockIdx.y * TS;   // post base
    int tx = threadIdx.x & 63, ty = threadIdx.x >> 6;

    const float* W; int ldw, po_off, pr_off; float sign;
    bool preE = (P0 < N_E), postE = (Q0 < N_E);
    if (postE && preE)        { W = Wee; ldw = N_E; po_off = 0;   pr_off = 0;   sign =  1.f; }
    else if (!postE && preE)  { W = Wie; ldw = N_E; po_off = N_E; pr_off = 0;   sign =  1.f; }
    else if (postE && !preE)  { W = Wei; ldw = N_I; po_off = 0;   pr_off = N_E; sign = -1.f; }
    else                      { W = Wii; ldw = N_I; po_off = N_E; pr_off = N_E; sign = -1.f; }

    for (int r = ty; r < TS; r += 4) {
        int post = Q0 + r, pre = P0 + tx;
        float v = W[(size_t)(post - po_off) * ldw + (pre - pr_off)];
        tile[r][tx] = (v > 0.f) ? sign * v : 0.f;
    }
    __syncthreads();
    for (int r = ty; r < TS; r += 4) {
        int pre = P0 + r, post = Q0 + tx;
        Wd[(size_t)pre * N_TOT + post] = __float2half(tile[tx][r]);
    }
}

// ------------------------------------------------------------------
// Input projection GEMM (unchanged)
// ------------------------------------------------------------------
#define PBM 128
#define PBN 64
#define PBK 32
__global__ __launch_bounds__(256) void proj_kernel(
    const float* __restrict__ x, const float* __restrict__ We, const float* __restrict__ Wi,
    float* __restrict__ out, int t0)
{
    __shared__ __align__(16) float As[PBK][132];
    __shared__ __align__(16) float Bs[PBK][68];
    int tid = threadIdx.x;
    int bx = blockIdx.x, by = blockIdx.y;
    int tx = tid & 15, ty = tid >> 4;
    float acc[8][4];
#pragma unroll
    for (int i = 0; i < 8; ++i)
#pragma unroll
        for (int j = 0; j < 4; ++j) acc[i][j] = 0.0f;

    for (int kb = 0; kb < INDIM; kb += PBK) {
#pragma unroll
        for (int it = 0; it < 4; ++it) {
            int idx = it * 256 + tid;
            int kq = idx & 7, ml = idx >> 3;
            int m = by * PBM + ml;
            int b = m & 63, tl = m >> 6;
            const float* arow = x + ((size_t)b * TSTEPS + (size_t)(t0 + tl)) * INDIM;
            float4 v = *(const float4*)(arow + kb + kq * 4);
            As[kq * 4 + 0][ml] = v.x; As[kq * 4 + 1][ml] = v.y;
            As[kq * 4 + 2][ml] = v.z; As[kq * 4 + 3][ml] = v.w;
        }
#pragma unroll
        for (int it = 0; it < 2; ++it) {
            int idx = it * 256 + tid;
            int kq = idx & 7, nl = idx >> 3;
            int n = bx * PBN + nl;
            const float* brow = (n < N_E) ? (We + (size_t)n * INDIM)
                                          : (Wi + (size_t)(n - N_E) * INDIM);
            float4 v = *(const float4*)(brow + kb + kq * 4);
            Bs[kq * 4 + 0][nl] = v.x; Bs[kq * 4 + 1][nl] = v.y;
            Bs[kq * 4 + 2][nl] = v.z; Bs[kq * 4 + 3][nl] = v.w;
        }
        __syncthreads();
#pragma unroll
        for (int k = 0; k < PBK; ++k) {
            float4 a0 = *(const float4*)&As[k][ty * 8];
            float4 a1 = *(const float4*)&As[k][ty * 8 + 4];
            float4 b0 = *(const float4*)&Bs[k][tx * 4];
            float a[8] = {a0.x, a0.y, a0.z, a0.w, a1.x, a1.y, a1.z, a1.w};
            float bb[4] = {b0.x, b0.y, b0.z, b0.w};
#pragma unroll
            for (int i = 0; i < 8; ++i)
#pragma unroll
                for (int j = 0; j < 4; ++j)
                    acc[i][j] = fmaf(a[i], bb[j], acc[i][j]);
        }
        __syncthreads();
    }
#pragma unroll
    for (int i = 0; i < 8; ++i) {
        int m = by * PBM + ty * 8 + i;
        float4 o = make_float4(acc[i][0], acc[i][1], acc[i][2], acc[i][3]);
        *(float4*)(out + (size_t)m * N_TOT + bx * PBN + tx * 4) = o;
    }
}

__device__ __forceinline__ float inline_proj(const float* __restrict__ x,
                                             const float* __restrict__ We_in,
                                             const float* __restrict__ Wi_in,
                                             int b, int t, int n)
{
    const float* xr = x + ((size_t)b * TSTEPS + (size_t)t) * INDIM;
    const float* wr = (n < N_E) ? (We_in + (size_t)n * INDIM)
                                : (Wi_in + (size_t)(n - N_E) * INDIM);
    float a = 0.f;
#pragma unroll
    for (int k = 0; k < INDIM; k += 4) {
        float4 w = *(const float4*)(wr + k);
        float4 xv = *(const float4*)(xr + k);
        a = fmaf(w.x, xv.x, a); a = fmaf(w.y, xv.y, a);
        a = fmaf(w.z, xv.z, a); a = fmaf(w.w, xv.w, a);
    }
    return a;
}

// ------------------------------------------------------------------
// PULL sim: 32-deep predicated batched gather (one memory round trip
// for ns<=32) + register prefetch of next-step input. No LDS
// accumulator, no synaptic atomics; 2 barriers/step.
// ------------------------------------------------------------------
__global__ __launch_bounds__(640) void sim_kernel(
    const float* __restrict__ i_inp,
    const float* __restrict__ x, const float* __restrict__ We_in, const float* __restrict__ Wi_in,
    const __half* __restrict__ Wd,
    float* __restrict__ gv, float* __restrict__ gi, unsigned* __restrict__ g_cnt,
    int* __restrict__ g_list, int* __restrict__ g_nspk,
    int t0, int tc, int first)
{
    __shared__ int list_s[2][N_TOT];
    __shared__ int nspk_s[2];

    int b = blockIdx.x, tid = threadIdx.x, lane = tid & 63;
    int p0 = tid * 4;
    bool isE = (tid < 512);
    float tm = isE ? 0.05f : 0.1f;

    float v0, v1, v2, v3, c0, c1, c2, c3;
    unsigned n0c = 0u, n1c = 0u, n2c = 0u, n3c = 0u;
    if (first) {
        v0 = v1 = v2 = v3 = 0.f; c0 = c1 = c2 = c3 = 0.f;
        if (tid == 0) nspk_s[0] = 0;
    } else {
        float4 vv = *(const float4*)(gv + (size_t)b * N_TOT + p0);
        float4 cc = *(const float4*)(gi + (size_t)b * N_TOT + p0);
        v0 = vv.x; v1 = vv.y; v2 = vv.z; v3 = vv.w;
        c0 = cc.x; c1 = cc.y; c2 = cc.z; c3 = cc.w;
        if (isE) {
            uint4 q = *(const uint4*)(g_cnt + (size_t)b * N_E + p0);
            n0c = q.x; n1c = q.y; n2c = q.z; n3c = q.w;
        }
        if (tid == 0) nspk_s[0] = g_nspk[b];
    }
    __syncthreads();
    if (!first) {
        int n0 = nspk_s[0];
        for (int s = tid; s < n0; s += 640) list_s[0][s] = g_list[(size_t)b * N_TOT + s];
    }
    __syncthreads();

    const unsigned short* Wdu = (const unsigned short*)Wd;

    float4 pf;
    if (i_inp) pf = *(const float4*)(i_inp + (size_t)b * N_TOT + p0);

    for (int tl = 0; tl < tc; ++tl) {
        int cur = tl & 1, nxt = cur ^ 1;
        if (tid == 0) nspk_s[nxt] = 0;

        float I0, I1, I2, I3;
        float4 pfn;
        if (i_inp) {
            I0 = pf.x; I1 = pf.y; I2 = pf.z; I3 = pf.w;
            if (tl + 1 < tc)
                pfn = *(const float4*)(i_inp + ((size_t)(tl + 1) * BATCH + b) * N_TOT + p0);
        } else {
            const float* xr = x + ((size_t)b * TSTEPS + (size_t)(t0 + tl)) * INDIM;
            const float* w0 = isE ? (We_in + (size_t)p0 * INDIM)
                                  : (Wi_in + (size_t)(p0 - N_E) * INDIM);
            I0 = I1 = I2 = I3 = 0.f;
            for (int k = 0; k < INDIM; ++k) {
                float xv = xr[k];
                I0 = fmaf(w0[k], xv, I0);
                I1 = fmaf(w0[INDIM + k], xv, I1);
                I2 = fmaf(w0[2 * INDIM + k], xv, I2);
                I3 = fmaf(w0[3 * INDIM + k], xv, I3);
            }
        }

        // gather: batched predicated loads, all issued before any use
        int ns = nspk_s[cur];
        const int* lst = list_s[cur];
        for (int s0 = 0; s0 < ns; s0 += GD) {
            int take = ns - s0; if (take > GD) take = GD;
            ushort4 w[GD];
#pragma unroll
            for (int k = 0; k < GD; ++k) {
                if (k < take) {
                    int j = lst[s0 + k];
                    w[k] = *(const ushort4*)(Wdu + (size_t)j * N_TOT + p0);
                }
            }
#pragma unroll
            for (int k = 0; k < GD; ++k) {
                if (k < take) {
                    I0 += __half2float(__ushort_as_half(w[k].x));
                    I1 += __half2float(__ushort_as_half(w[k].y));
                    I2 += __half2float(__ushort_as_half(w[k].z));
                    I3 += __half2float(__ushort_as_half(w[k].w));
                }
            }
        }

        // LIF in registers
        float vd0 = v0 + tm * (c0 - v0); bool z0 = vd0 > 1.0f; v0 = z0 ? 0.f : vd0; c0 = 0.8f * c0 + I0;
        float vd1 = v1 + tm * (c1 - v1); bool z1 = vd1 > 1.0f; v1 = z1 ? 0.f : vd1; c1 = 0.8f * c1 + I1;
        float vd2 = v2 + tm * (c2 - v2); bool z2 = vd2 > 1.0f; v2 = z2 ? 0.f : vd2; c2 = 0.8f * c2 + I2;
        float vd3 = v3 + tm * (c3 - v3); bool z3 = vd3 > 1.0f; v3 = z3 ? 0.f : vd3; c3 = 0.8f * c3 + I3;
        if (isE) { n0c += z0; n1c += z1; n2c += z2; n3c += z3; }

        __syncthreads();   // barrier 1: all gathers of cur done; reset of nxt visible

        unsigned long long m0 = __ballot(z0), m1 = __ballot(z1);
        unsigned long long m2 = __ballot(z2), m3 = __ballot(z3);
        int w0c = __popcll(m0), w1c = __popcll(m1), w2c = __popcll(m2), w3c = __popcll(m3);
        int tot = w0c + w1c + w2c + w3c;
        if (tot) {
            int base = 0;
            if (lane == 0) base = atomicAdd(&nspk_s[nxt], tot);
            base = __shfl(base, 0);
            unsigned long long pre = (1ull << lane) - 1ull;
            if (z0) list_s[nxt][base + __popcll(m0 & pre)] = p0;
            if (z1) list_s[nxt][base + w0c + __popcll(m1 & pre)] = p0 + 1;
            if (z2) list_s[nxt][base + w0c + w1c + __popcll(m2 & pre)] = p0 + 2;
            if (z3) list_s[nxt][base + w0c + w1c + w2c + __popcll(m3 & pre)] = p0 + 3;
        }
        __syncthreads();   // barrier 2: appends complete
        pf = pfn;
    }

    *(float4*)(gv + (size_t)b * N_TOT + p0) = make_float4(v0, v1, v2, v3);
    *(float4*)(gi + (size_t)b * N_TOT + p0) = make_float4(c0, c1, c2, c3);
    if (isE) *(uint4*)(g_cnt + (size_t)b * N_E + p0) = make_uint4(n0c, n1c, n2c, n3c);
    int fin = tc & 1;
    if (tid == 0) g_nspk[b] = nspk_s[fin];
    for (int s = tid; s < nspk_s[fin]; s += 640) g_list[(size_t)b * N_TOT + s] = list_s[fin][s];
}

// ------------------------------------------------------------------
// Readout
// ------------------------------------------------------------------
__global__ __launch_bounds__(256) void readout_kernel(
    const unsigned* __restrict__ g_cnt,
    const float* __restrict__ rw, const float* __restrict__ rb, float* __restrict__ out)
{
    int b = blockIdx.x, tid = threadIdx.x;
    float a0 = 0.f, a1 = 0.f, a2 = 0.f;
    for (int n = tid; n < N_E; n += 256) {
        float c = (float)g_cnt[(size_t)b * N_E + n];
        a0 = fmaf(c, rw[n], a0);
        a1 = fmaf(c, rw[N_E + n], a1);
        a2 = fmaf(c, rw[2 * N_E + n], a2);
    }
#pragma unroll
    for (int off = 32; off > 0; off >>= 1) {
        a0 += __shfl_down(a0, off);
        a1 += __shfl_down(a1, off);
        a2 += __shfl_down(a2, off);
    }
    __shared__ float part[3][4];
    int wid = tid >> 6, lane = tid & 63;
    if (lane == 0) { part[0][wid] = a0; part[1][wid] = a1; part[2][wid] = a2; }
    __syncthreads();
    if (tid == 0) {
        float s0 = part[0][0] + part[0][1] + part[0][2] + part[0][3];
        float s1 = part[1][0] + part[1][1] + part[1][2] + part[1][3];
        float s2 = part[2][0] + part[2][1] + part[2][2] + part[2][3];
        const float inv = 1.0f / 512.0f;
        out[b * 3 + 0] = fmaf(s0, inv, rb[0]);
        out[b * 3 + 1] = fmaf(s1, inv, rb[1]);
        out[b * 3 + 2] = fmaf(s2, inv, rb[2]);
    }
}

// ------------------------------------------------------------------
extern "C" void kernel_launch(void* const* d_in, const int* in_sizes, int n_in,
                              void* d_out, int out_size, void* d_ws, size_t ws_size,
                              hipStream_t stream)
{
    const float* x     = (const float*)d_in[0];
    const float* Wee   = (const float*)d_in[1];
    const float* Wie   = (const float*)d_in[2];
    const float* Wei   = (const float*)d_in[3];
    const float* Wii   = (const float*)d_in[4];
    const float* We_in = (const float*)d_in[5];
    const float* Wi_in = (const float*)d_in[6];
    const float* rw    = (const float*)d_in[7];
    const float* rb    = (const float*)d_in[8];
    float* out = (float*)d_out;
    char* ws = (char*)d_ws;

    size_t off = 0;
    auto alloc = [&](size_t bytes) {
        size_t o = off;
        off = (off + bytes + 255) & ~(size_t)255;
        return o;
    };
    size_t o_wd    = alloc((size_t)N_TOT * N_TOT * 2);        // 13.1 MB dense fp16
    size_t o_gv    = alloc((size_t)BATCH * N_TOT * 4);
    size_t o_gi    = alloc((size_t)BATCH * N_TOT * 4);
    size_t o_gcnt  = alloc((size_t)BATCH * N_E * 4);
    size_t o_glist = alloc((size_t)BATCH * N_TOT * 4);
    size_t o_gnspk = alloc((size_t)BATCH * 4);
    size_t o_iinp  = off;   // remainder for the input-projection chunk

    int tc = 0;
    if (ws_size > o_iinp) {
        size_t avail = ws_size - o_iinp;
        tc = TSTEPS;
        while (tc >= 2 && (size_t)tc * BATCH * N_TOT * 4 > avail) tc >>= 1;
        if (tc < 2) tc = 0;
    }

    __half*   p_wd    = (__half*)(ws + o_wd);
    float*    p_gv    = (float*)(ws + o_gv);
    float*    p_gi    = (float*)(ws + o_gi);
    unsigned* p_gcnt  = (unsigned*)(ws + o_gcnt);
    int*      p_glist = (int*)(ws + o_glist);
    int*      p_gnspk = (int*)(ws + o_gnspk);
    float*    p_iinp  = (float*)(ws + o_iinp);

    // ---- build dense signed-relu fp16 table ----
    dim3 wg(N_TOT / TS, N_TOT / TS);
    build_wd_kernel<<<wg, 256, 0, stream>>>(Wee, Wie, Wei, Wii, p_wd);

    // ---- time loop: proj GEMM chunk + persistent sim ----
    if (tc >= 2) {
        for (int t0 = 0; t0 < TSTEPS; t0 += tc) {
            dim3 pg(N_TOT / PBN, (tc * BATCH) / PBM);
            proj_kernel<<<pg, 256, 0, stream>>>(x, We_in, Wi_in, p_iinp, t0);
            sim_kernel<<<BATCH, 640, 0, stream>>>(
                p_iinp, x, We_in, Wi_in, p_wd,
                p_gv, p_gi, p_gcnt, p_glist, p_gnspk,
                t0, tc, (t0 == 0) ? 1 : 0);
        }
    } else {
        sim_kernel<<<BATCH, 640, 0, stream>>>(
            nullptr, x, We_in, Wi_in, p_wd,
            p_gv, p_gi, p_gcnt, p_glist, p_gnspk,
            0, TSTEPS, 1);
    }

    // ---- readout ----
    readout_kernel<<<BATCH, 256, 0, stream>>>(p_gcnt, rw, rb, out);
}